// Round 5
// baseline (269.821 us; speedup 1.0000x reference)
//
#include <hip/hip_runtime.h>
#include <climits>

// StreamingRhythmProjector: B=4096 rows x U=2048 units, one 256-thread block
// (4 waves) per row, 8 elems/thread.
// R5: issue ALL 12 float4 input loads up front into named registers (48 VGPRs
// of load data in flight) to restore memory-level parallelism; R2/R4's
// VGPR_Count of 28-32 proved the allocator was serializing loads.
// __launch_bounds__(256,2) gives the allocator room (<=256 VGPRs).

constexpr int UNITS = 2048;
constexpr int BLOCK = 256;
constexpr int EPT = UNITS / BLOCK;  // 8 elems/thread = 2 float4 chunks

typedef float f32x4 __attribute__((ext_vector_type(4)));

static __device__ __forceinline__ float waveSum(float v) {
#pragma unroll
  for (int m = 1; m < 64; m <<= 1) v += __shfl_xor(v, m, 64);
  return v;  // all lanes hold the sum
}
static __device__ __forceinline__ int waveMin(int v) {
#pragma unroll
  for (int m = 1; m < 64; m <<= 1) v = min(v, __shfl_xor(v, m, 64));
  return v;
}

__global__ __launch_bounds__(BLOCK, 2) void rhythm_kernel(
    const float* __restrict__ dur_anchor,    // [B,U]
    const float* __restrict__ unit_mask,     // [B,U] prefix mask (0/1)
    const float* __restrict__ speech_budget, // [B]
    const float* __restrict__ pause_budget,  // [B]
    const float* __restrict__ dur_logratio,  // [B,U]
    const float* __restrict__ pause_weight,  // [B,U]
    const float* __restrict__ boundary,      // [B,U]
    const float* __restrict__ phase_ptr,     // [B]
    const float* __restrict__ backlog,       // [B]
    const float* __restrict__ clock_delta,   // [B]
    const int*   __restrict__ commit_front,  // [B]
    const int*   __restrict__ open_run,      // [B,U]
    float* __restrict__ out,                 // f32, 3*B*U + 4*B
    int B) {
  const int row = blockIdx.x;
  const int t = threadIdx.x;
  const size_t base = (size_t)row * UNITS;
  const int e0 = 4 * t;           // chunk 0 element offset
  const int e1 = 1024 + 4 * t;    // chunk 1 element offset

  // per-row scalars (wave-uniform s_loads)
  const int prev = commit_front[row];
  const float sb = speech_budget[row];
  const float pb = pause_budget[row];
  const float pp = phase_ptr[row];
  const float bl = backlog[row];
  const float cd = clock_delta[row];

  // ---- issue ALL 12 vector loads before any consumption (max MLP) ----
  const float4 a_0 = *(const float4*)(dur_anchor   + base + e0);
  const float4 a_1 = *(const float4*)(dur_anchor   + base + e1);
  const float4 m_0 = *(const float4*)(unit_mask    + base + e0);
  const float4 m_1 = *(const float4*)(unit_mask    + base + e1);
  const float4 l_0 = *(const float4*)(dur_logratio + base + e0);
  const float4 l_1 = *(const float4*)(dur_logratio + base + e1);
  const float4 p_0 = *(const float4*)(pause_weight + base + e0);
  const float4 p_1 = *(const float4*)(pause_weight + base + e1);
  const float4 b_0 = *(const float4*)(boundary     + base + e0);
  const float4 b_1 = *(const float4*)(boundary     + base + e1);
  const int4   o_0 = *(const int4*)(open_run       + base + e0);
  const int4   o_1 = *(const int4*)(open_run       + base + e1);

  // ---- pass 1 compute: state = sr,sc only ----
  float sv_sr[EPT];  // masked speech_raw (0 where mask==0, else >= 1)
  float sv_sc[EPT];  // masked pause score
  float sum_sr = 0.f, sum_sc = 0.f, sum_m = 0.f;
  int min_open = INT_MAX;

  {
    const float av[8] = {a_0.x, a_0.y, a_0.z, a_0.w, a_1.x, a_1.y, a_1.z, a_1.w};
    const float mv[8] = {m_0.x, m_0.y, m_0.z, m_0.w, m_1.x, m_1.y, m_1.z, m_1.w};
    const float lv[8] = {l_0.x, l_0.y, l_0.z, l_0.w, l_1.x, l_1.y, l_1.z, l_1.w};
    const float pv[8] = {p_0.x, p_0.y, p_0.z, p_0.w, p_1.x, p_1.y, p_1.z, p_1.w};
    const float bv[8] = {b_0.x, b_0.y, b_0.z, b_0.w, b_1.x, b_1.y, b_1.z, b_1.w};
    const int   ov[8] = {o_0.x, o_0.y, o_0.z, o_0.w, o_1.x, o_1.y, o_1.z, o_1.w};
#pragma unroll
    for (int k = 0; k < 8; ++k) {
      const int idx = (k < 4) ? (e0 + k) : (e1 + k - 4);
      const float m = mv[k];
      const float a = fmaxf(av[k], 1.0f);                      // MIN_SPEECH_FRAMES
      const float bse = a * __expf(lv[k]);
      const float sr = fmaxf(fminf(bse, 3.0f * a), 1.0f) * m;  // MAX_SPEECH_EXPAND
      const float sc = fmaxf(pv[k], 0.0f) * (0.5f + bv[k]) * m;
      sv_sr[k] = sr;
      sv_sc[k] = sc;
      sum_sr += sr;
      sum_sc += sc;
      sum_m += m;
      // prefix mask => (idx < visible) <=> m == 1
      if (ov[k] > 0 && m > 0.5f) min_open = min(min_open, idx);
    }
  }

  // ---- reduction 1: wave butterfly + LDS cross-wave ----
  const int wv = t >> 6, ln = t & 63;
  __shared__ float sf[3][4];
  __shared__ int si[4];
  __shared__ float sg[2][4];  // reused for reduction 2

  const float r0 = waveSum(sum_sr);
  const float r1 = waveSum(sum_sc);
  const float r2 = waveSum(sum_m);
  const int ri = waveMin(min_open);
  if (ln == 0) { sf[0][wv] = r0; sf[1][wv] = r1; sf[2][wv] = r2; si[wv] = ri; }
  __syncthreads();

  // all 256 lanes combine the 4 partials (LDS broadcast) and compute scalars
  const float ts = sf[0][0] + sf[0][1] + sf[0][2] + sf[0][3];
  const float tc = sf[1][0] + sf[1][1] + sf[1][2] + sf[1][3];
  const float tm = sf[2][0] + sf[2][1] + sf[2][2] + sf[2][3];
  const int mo = min(min(si[0], si[1]), min(si[2], si[3]));

  const int visible = (int)(tm + 0.5f);               // exact: integer-valued f32
  const int closed = (mo == INT_MAX) ? visible : mo;
  const int relcap = max(visible - 2, 0);             // TAIL_HOLD_UNITS
  int cand = min(relcap, closed);
  const int bidx = min(max(cand - 1, 0), UNITS - 1);
  const float bval = boundary[base + bidx];           // uniform addr, cache-hot
  if (cand > 0 && cand < visible && bval < 0.45f)     // BOUNDARY_COMMIT_THRESHOLD
    cand = max(prev, cand - 1);
  const int commit = max(prev, cand);

  const float sscale = sb / fmaxf(ts, 1e-6f);
  const bool usefb = !(tc > 0.0f);
  const float pscale = pb / fmaxf(tc, 1e-6f);
  const float fbw = pb / fmaxf(tm, 1.0f);
  // analytic effective total (linearity): Sum eff = sscale*ts + pscale*tc
  const float eff_tot = usefb ? (sscale * ts + fbw * tm) : (sscale * ts + pscale * tc);

  // ---- tiny src range-sum: re-read dur_anchor over [prev,commit) (L2-warm) ----
  float src_rng = 0.f;
  for (int i = prev + t; i < commit; i += BLOCK) src_rng += dur_anchor[base + i];

  // ---- pass 2: outputs from registers + eff range sum ----
  float* __restrict__ out_speech = out;
  float* __restrict__ out_pause  = out + (size_t)B * UNITS;
  float* __restrict__ out_eff    = out + 2 * (size_t)B * UNITS;

  float eff_rng = 0.f;
#pragma unroll
  for (int c = 0; c < 2; ++c) {
    const int eb = (c == 0) ? e0 : e1;
    f32x4 s4, q4, e4;
#pragma unroll
    for (int j = 0; j < 4; ++j) {
      const int k = c * 4 + j;
      const int idx = eb + j;
      const float sr = sv_sr[k];
      const float m = (sr != 0.0f) ? 1.0f : 0.0f;     // exact: sr>=1 iff mask==1
      const float speech = sr * sscale;
      const float pause = usefb ? (m * fbw) : (sv_sc[k] * pscale);
      const float eff = (speech + pause) * m;
      s4[j] = speech;
      q4[j] = pause;
      e4[j] = eff;
      const bool inr = (idx >= prev) && (idx < commit);
      eff_rng += inr ? eff : 0.f;
    }
    __builtin_nontemporal_store(s4, (f32x4*)(out_speech + base + eb));
    __builtin_nontemporal_store(q4, (f32x4*)(out_pause + base + eb));
    __builtin_nontemporal_store(e4, (f32x4*)(out_eff + base + eb));
  }

  // ---- reduction 2: eff_rng, src_rng ----
  const float q0 = waveSum(eff_rng);
  const float q1 = waveSum(src_rng);
  if (ln == 0) { sg[0][wv] = q0; sg[1][wv] = q1; }
  __syncthreads();

  if (t == 0) {
    const float execp = sg[0][0] + sg[0][1] + sg[0][2] + sg[0][3];
    const float srcp  = sg[1][0] + sg[1][1] + sg[1][2] + sg[1][3];
    const bool adv = commit > prev;
    const float nclock = adv ? (cd + (execp - srcp)) : cd;
    const float nback = adv ? fmaxf(nclock, 0.0f) : bl;
    const float vt = fmaxf(eff_tot, 1.0f);
    const float nphase =
        adv ? fminf(fmaxf(pp + execp / vt, 0.0f), 1.0f) : pp;
    const size_t o = 3 * (size_t)B * UNITS;
    out[o + row] = (float)commit;
    out[o + (size_t)B + row] = nphase;
    out[o + 2 * (size_t)B + row] = nback;
    out[o + 3 * (size_t)B + row] = nclock;
  }
}

extern "C" void kernel_launch(void* const* d_in, const int* in_sizes, int n_in,
                              void* d_out, int out_size, void* d_ws, size_t ws_size,
                              hipStream_t stream) {
  const int B = in_sizes[7];  // phase_ptr length
  rhythm_kernel<<<dim3(B), dim3(BLOCK), 0, stream>>>(
      (const float*)d_in[0],   // dur_anchor_src
      (const float*)d_in[1],   // unit_mask
      (const float*)d_in[2],   // speech_budget_win
      (const float*)d_in[3],   // pause_budget_win
      (const float*)d_in[4],   // dur_logratio_unit
      (const float*)d_in[5],   // pause_weight_unit
      (const float*)d_in[6],   // boundary_latent
      (const float*)d_in[7],   // phase_ptr
      (const float*)d_in[8],   // backlog
      (const float*)d_in[9],   // clock_delta
      (const int*)d_in[10],    // commit_frontier
      (const int*)d_in[11],    // open_run_mask
      (float*)d_out, B);
}